// Round 1
// baseline (4464.496 us; speedup 1.0000x reference)
//
#include <hip/hip_runtime.h>
#include <hip/hip_bf16.h>
#include <stdint.h>

// Problem dims
#define BB 64
#define SS 512
#define EE 256
#define HH 512
#define K5 2560
#define NWG 32   // scan workgroups; each owns 16 hidden cols (x5 gates = 80 W cols)

typedef short s16x8 __attribute__((ext_vector_type(8)));
typedef float vf4 __attribute__((ext_vector_type(4)));

// Workspace byte offsets (all 256B aligned). Total = 205,621,248 B (~196.1 MiB)
#define OFF_WBT   0UL           // W bf16 transposed [2560][768]
#define OFF_EMB   3932160UL     // embedding bf16 [100][256]
#define OFF_WIT   3983360UL     // Wi bf16 transposed+padded [112][512]
#define OFF_DTT   4098048UL     // time_deltas transposed f32 [512][64]
#define OFF_FLAGS 4229120UL     // int flags [512][32]
#define OFF_HBUF  4294656UL     // h bf16 [512][64][512]
#define OFF_ZXP   37849088UL    // zx bf16, MFMA-frag-permuted [512][32][4][5][64][4]

__device__ __forceinline__ unsigned short f2bf(float f) {
  unsigned u = __float_as_uint(f);
  u += 0x7fffu + ((u >> 16) & 1u);   // round-to-nearest-even
  return (unsigned short)(u >> 16);
}
__device__ __forceinline__ float bf2f(unsigned short h) {
  return __uint_as_float(((unsigned)h) << 16);
}
__device__ __forceinline__ float sigmoidf_(float x) { return 1.f / (1.f + __expf(-x)); }
__device__ __forceinline__ float softplusf_(float x) {
  return fmaxf(x, 0.f) + log1pf(__expf(-fabsf(x)));
}
__device__ __forceinline__ float tanhf_(float x) {   // overflow-safe
  float e = __expf(2.f * x);
  return 1.f - 2.f / (e + 1.f);
}

// ---------------- init: dtype conversions / transposes / flag zeroing ----------------
__global__ void init_kernel(const float* __restrict__ W, const float* __restrict__ emb,
                            const float* __restrict__ Wi, const float* __restrict__ td,
                            unsigned short* __restrict__ WbT, unsigned short* __restrict__ embB,
                            unsigned short* __restrict__ WiT, float* __restrict__ dtT,
                            int* __restrict__ flags) {
  unsigned i = blockIdx.x * 256u + threadIdx.x;
  if (i < 1966080u) {               // WbT[c][k] = bf16(W[k][c])
    unsigned c = i / 768u, k = i % 768u;
    WbT[i] = f2bf(W[(size_t)k * 2560u + c]);
    return;
  }
  i -= 1966080u;
  if (i < 25600u) { embB[i] = f2bf(emb[i]); return; }
  i -= 25600u;
  if (i < 57344u) {                 // WiT[c][k] = bf16(Wi[k][c]), pad c=100..111 with 0
    unsigned c = i / 512u, k = i % 512u;
    WiT[i] = f2bf(c < 100u ? Wi[(size_t)k * 100u + c] : 0.f);
    return;
  }
  i -= 57344u;
  if (i < 32768u) {                 // dtT[t][b] = td[b][t]
    unsigned t = i / 64u, b = i % 64u;
    dtT[i] = td[(size_t)b * 512u + t];
    return;
  }
  i -= 32768u;
  if (i < 16384u) { flags[i] = 0; return; }
}

// ---------------- zx = gather(embedding) @ W_x + b, stored bf16 in frag-permuted layout ----
__global__ __launch_bounds__(256, 2)
void zx_kernel(const int* __restrict__ evt, const unsigned short* __restrict__ embB,
               const unsigned short* __restrict__ WbT, const float* __restrict__ bias,
               unsigned short* __restrict__ zxp) {
  const int t = blockIdx.y;
  const int tid = threadIdx.x;
  const int v = tid >> 6, lane = tid & 63;
  const int m = lane & 15, quad = lane >> 4;
  const int cbase = blockIdx.x * 256 + v * 64;  // wave's 64 output cols (4 frags)

  // Preload B frags (W_x rows 0..255): Breg[ch][cf], k = ch*32 + quad*8 + j
  s16x8 Breg[8][4];
#pragma unroll
  for (int cf = 0; cf < 4; ++cf) {
    const unsigned short* bp = WbT + (size_t)(cbase + cf * 16 + m) * 768 + quad * 8;
#pragma unroll
    for (int ch = 0; ch < 8; ++ch) Breg[ch][cf] = *(const s16x8*)(bp + ch * 32);
  }
  int ev[4];
#pragma unroll
  for (int rt = 0; rt < 4; ++rt) ev[rt] = evt[(size_t)(rt * 16 + m) * 512 + t];

  vf4 acc[4][4];
#pragma unroll
  for (int cf = 0; cf < 4; ++cf) {
    float bbv = bias[cbase + cf * 16 + m];
#pragma unroll
    for (int rt = 0; rt < 4; ++rt) acc[rt][cf] = (vf4){bbv, bbv, bbv, bbv};
  }
#pragma unroll
  for (int ch = 0; ch < 8; ++ch) {
#pragma unroll
    for (int rt = 0; rt < 4; ++rt) {
      s16x8 a = *(const s16x8*)(embB + (size_t)ev[rt] * 256 + ch * 32 + quad * 8);
#pragma unroll
      for (int cf = 0; cf < 4; ++cf)
        acc[rt][cf] = __builtin_amdgcn_mfma_f32_16x16x32_bf16(a, Breg[ch][cf], acc[rt][cf], 0, 0, 0);
    }
  }
#pragma unroll
  for (int cf = 0; cf < 4; ++cf) {
    int col0 = cbase + cf * 16;
    int g = col0 >> 9;              // gate index
    int w = (col0 & 511) >> 4;      // scan WG owning these cols
#pragma unroll
    for (int rt = 0; rt < 4; ++rt) {
      unsigned h0 = f2bf(acc[rt][cf][0]);
      unsigned h1 = f2bf(acc[rt][cf][1]);
      unsigned h2 = f2bf(acc[rt][cf][2]);
      unsigned h3 = f2bf(acc[rt][cf][3]);
      uint2 val;
      val.x = h0 | (h1 << 16);
      val.y = h2 | (h3 << 16);
      ((uint2*)zxp)[((((size_t)t * 32 + w) * 4 + rt) * 5 + g) * 64 + lane] = val;
    }
  }
}

// ---------------- persistent sequential scan: 32 WGs, flag-synced per step ----------------
__global__ __launch_bounds__(256, 1)
void scan_kernel(const unsigned short* __restrict__ WbT,
                 const unsigned short* __restrict__ zxp,
                 const float* __restrict__ dtT,
                 unsigned short* __restrict__ hbuf,
                 int* __restrict__ flags,
                 float* __restrict__ out_h, float* __restrict__ out_d) {
  const int w = blockIdx.x;           // 0..31, owns hidden cols [w*16, w*16+16)
  const int tid = threadIdx.x;
  const int v = tid >> 6, lane = tid & 63;  // wave v owns batch rows [v*16, v*16+16)
  const int m = lane & 15, quad = lane >> 4;
  const int rowb = v * 16;
  const int bb0 = rowb + quad * 4;    // first batch row of this lane's C-frag elems
  const int col = w * 16 + m;         // hidden col of this lane's C-frag elems

  // W_h slice resident in registers: Breg[ch][g], k = 256 + ch*32 + quad*8 + j
  s16x8 Breg[16][5];
#pragma unroll
  for (int g = 0; g < 5; ++g) {
    const unsigned short* bp = WbT + (size_t)(g * 512 + w * 16 + m) * 768 + 256 + quad * 8;
#pragma unroll
    for (int ch = 0; ch < 16; ++ch) Breg[ch][g] = *(const s16x8*)(bp + ch * 32);
  }

  vf4 cst = (vf4){0.f, 0.f, 0.f, 0.f};   // cell state (4 rows x this lane's col)

  for (int t = 0; t < 512; ++t) {
    // acc init from zx (independent of recurrence -> issue before flag wait)
    vf4 acc[5];
#pragma unroll
    for (int g = 0; g < 5; ++g) {
      uint2 zv = ((const uint2*)zxp)[((((size_t)t * 32 + w) * 4 + v) * 5 + g) * 64 + lane];
      acc[g][0] = bf2f((unsigned short)(zv.x & 0xffffu));
      acc[g][1] = bf2f((unsigned short)(zv.x >> 16));
      acc[g][2] = bf2f((unsigned short)(zv.y & 0xffffu));
      acc[g][3] = bf2f((unsigned short)(zv.y >> 16));
    }
    vf4 dt4 = *(const vf4*)(dtT + t * 64 + bb0);

    if (t > 0) {
      // wait until all 32 WGs have published h[t-1]
      const int* fp = flags + (t - 1) * NWG + (lane & 31);
      while (__hip_atomic_load(fp, __ATOMIC_RELAXED, __HIP_MEMORY_SCOPE_AGENT) == 0) {
        __builtin_amdgcn_s_sleep(1);
      }
      __builtin_amdgcn_fence(__ATOMIC_ACQUIRE, "agent");
      // A-frags straight from global h buffer: A[m][k], row = rowb+m
      const unsigned short* hsrc =
          hbuf + (size_t)(t - 1) * (BB * HH) + (size_t)(rowb + m) * HH + quad * 8;
#pragma unroll
      for (int ch = 0; ch < 16; ++ch) {
        s16x8 a = *(const s16x8*)(hsrc + ch * 32);
#pragma unroll
        for (int g = 0; g < 5; ++g)
          acc[g] = __builtin_amdgcn_mfma_f32_16x16x32_bf16(a, Breg[ch][g], acc[g], 0, 0, 0);
      }
    }

    // gates + state update + outputs (frag layouts of all 5 gates coincide elementwise)
#pragma unroll
    for (int r = 0; r < 4; ++r) {
      float i_ = sigmoidf_(acc[0][r]);
      float f_ = sigmoidf_(acc[1][r]);
      float o_ = sigmoidf_(acc[2][r]);
      float g_ = tanhf_(acc[3][r]);
      float dec = softplusf_(acc[4][r]);
      float cn = f_ * cst[r] + i_ * g_;
      float ct = cn * __expf(-dec * dt4[r]);
      float h_ = o_ * tanhf_(ct);
      cst[r] = ct;
      int b_ = bb0 + r;
      size_t oo = ((size_t)b_ * SS + t) * HH + col;
      out_h[oo] = h_;
      out_d[oo] = dec;
      __hip_atomic_store(hbuf + (size_t)t * (BB * HH) + (size_t)b_ * HH + col, f2bf(h_),
                         __ATOMIC_RELAXED, __HIP_MEMORY_SCOPE_AGENT);
    }
    __syncthreads();  // all waves' agent-scope stores drained (vmcnt) before publishing
    if (tid == 0)
      __hip_atomic_store(flags + t * NWG + w, 1, __ATOMIC_RELEASE, __HIP_MEMORY_SCOPE_AGENT);
  }
}

// ---------------- base_intensities = softplus(h @ Wi + bi) ----------------
__global__ __launch_bounds__(256, 2)
void inten_kernel(const unsigned short* __restrict__ hbuf,
                  const unsigned short* __restrict__ WiT,
                  const float* __restrict__ bi,
                  float* __restrict__ out_i) {
  const int b = blockIdx.y;            // batch row
  const int t0 = blockIdx.x * 64;      // 64 timesteps per WG
  const int tid = threadIdx.x;
  const int v = tid >> 6, lane = tid & 63;
  const int m = lane & 15, quad = lane >> 4;
  const int trow = t0 + v * 16 + m;    // A row = timestep

  vf4 acc[7];
#pragma unroll
  for (int cf = 0; cf < 7; ++cf) {
    int c = cf * 16 + m;
    float bbv = (c < 100) ? bi[c] : 0.f;
    acc[cf] = (vf4){bbv, bbv, bbv, bbv};
  }
  const unsigned short* ha = hbuf + ((size_t)trow * 64 + b) * 512 + quad * 8;
#pragma unroll 4
  for (int ch = 0; ch < 16; ++ch) {
    s16x8 a = *(const s16x8*)(ha + ch * 32);
#pragma unroll
    for (int cf = 0; cf < 7; ++cf) {
      s16x8 bf = *(const s16x8*)(WiT + (size_t)(cf * 16 + m) * 512 + ch * 32 + quad * 8);
      acc[cf] = __builtin_amdgcn_mfma_f32_16x16x32_bf16(a, bf, acc[cf], 0, 0, 0);
    }
  }
#pragma unroll
  for (int cf = 0; cf < 7; ++cf) {
    int c = cf * 16 + m;
#pragma unroll
    for (int r = 0; r < 4; ++r) {
      int tt = t0 + v * 16 + quad * 4 + r;
      if (c < 100) out_i[((size_t)b * 512 + tt) * 100 + c] = softplusf_(acc[cf][r]);
    }
  }
}

extern "C" void kernel_launch(void* const* d_in, const int* in_sizes, int n_in,
                              void* d_out, int out_size, void* d_ws, size_t ws_size,
                              hipStream_t stream) {
  (void)in_sizes; (void)n_in; (void)out_size; (void)ws_size;
  const int*   evt  = (const int*)d_in[0];
  const float* td   = (const float*)d_in[1];
  const float* emb  = (const float*)d_in[2];
  const float* W    = (const float*)d_in[3];
  const float* bias = (const float*)d_in[4];
  const float* Wi   = (const float*)d_in[5];
  const float* bi   = (const float*)d_in[6];

  char* ws = (char*)d_ws;
  unsigned short* WbT  = (unsigned short*)(ws + OFF_WBT);
  unsigned short* embB = (unsigned short*)(ws + OFF_EMB);
  unsigned short* WiT  = (unsigned short*)(ws + OFF_WIT);
  float*          dtT  = (float*)(ws + OFF_DTT);
  int*            flags= (int*)(ws + OFF_FLAGS);
  unsigned short* hbuf = (unsigned short*)(ws + OFF_HBUF);
  unsigned short* zxp  = (unsigned short*)(ws + OFF_ZXP);

  float* out_h = (float*)d_out;
  float* out_d = out_h + (size_t)BB * SS * HH;
  float* out_i = out_d + (size_t)BB * SS * HH;

  init_kernel<<<8196, 256, 0, stream>>>(W, emb, Wi, td, WbT, embB, WiT, dtT, flags);
  zx_kernel<<<dim3(10, 512), 256, 0, stream>>>(evt, embB, WbT, bias, zxp);
  scan_kernel<<<NWG, 256, 0, stream>>>(WbT, zxp, dtT, hbuf, flags, out_h, out_d);
  inten_kernel<<<dim3(8, 64), 256, 0, stream>>>(hbuf, WiT, bi, out_i);
}

// Round 2
// 3703.239 us; speedup vs baseline: 1.2056x; 1.2056x over previous
//
#include <hip/hip_runtime.h>
#include <hip/hip_bf16.h>
#include <stdint.h>

// Problem dims
#define BB 64
#define SS 512
#define EE 256
#define HH 512
#define NWG 32   // scan workgroups; each owns 16 hidden cols (x5 gates = 80 W cols)

typedef short s16x8 __attribute__((ext_vector_type(8)));
typedef float vf4 __attribute__((ext_vector_type(4)));

// Workspace byte offsets (all 256B aligned). Total = 205,817,856 B (~196.3 MiB)
#define OFF_WBT   0UL           // W bf16 transposed [2560][768]
#define OFF_EMB   3932160UL     // embedding bf16 [100][256]
#define OFF_WIT   3983360UL     // Wi bf16 transposed+padded [112][512]
#define OFF_DTT   4098048UL     // time_deltas transposed f32 [512][64]
#define OFF_FLAGS 4229120UL     // int flags, 65536 dwords (per (t,w,v), line-sharded)
#define OFF_HBUF  4491264UL     // h bf16 [512][64][512]
#define OFF_ZXP   38045696UL    // zx bf16, MFMA-frag-permuted [512][32][4][5][64][4]

// flag dword index: line (64B) per (t-block, w, v); t packed 16-per-line.
// Pollers of one line = lane w of wave v in each of 32 WGs -> 32 pollers/line.
__device__ __forceinline__ int fidx(int t, int w, int v) {
  return (((t >> 4) * 128) + w * 4 + v) * 16 + (t & 15);
}

__device__ __forceinline__ unsigned short f2bf(float f) {
  unsigned u = __float_as_uint(f);
  u += 0x7fffu + ((u >> 16) & 1u);   // round-to-nearest-even
  return (unsigned short)(u >> 16);
}
__device__ __forceinline__ float bf2f(unsigned short h) {
  return __uint_as_float(((unsigned)h) << 16);
}
__device__ __forceinline__ float sigmoidf_(float x) { return 1.f / (1.f + __expf(-x)); }
__device__ __forceinline__ float softplusf_(float x) {
  return fmaxf(x, 0.f) + log1pf(__expf(-fabsf(x)));
}
__device__ __forceinline__ float tanhf_(float x) {   // overflow-safe
  float e = __expf(2.f * x);
  return 1.f - 2.f / (e + 1.f);
}

// ---------------- init: dtype conversions / transposes / flag zeroing ----------------
__global__ void init_kernel(const float* __restrict__ W, const float* __restrict__ emb,
                            const float* __restrict__ Wi, const float* __restrict__ td,
                            unsigned short* __restrict__ WbT, unsigned short* __restrict__ embB,
                            unsigned short* __restrict__ WiT, float* __restrict__ dtT,
                            int* __restrict__ flags) {
  unsigned i = blockIdx.x * 256u + threadIdx.x;
  if (i < 1966080u) {               // WbT[c][k] = bf16(W[k][c])
    unsigned c = i / 768u, k = i % 768u;
    WbT[i] = f2bf(W[(size_t)k * 2560u + c]);
    return;
  }
  i -= 1966080u;
  if (i < 25600u) { embB[i] = f2bf(emb[i]); return; }
  i -= 25600u;
  if (i < 57344u) {                 // WiT[c][k] = bf16(Wi[k][c]), pad c=100..111 with 0
    unsigned c = i / 512u, k = i % 512u;
    WiT[i] = f2bf(c < 100u ? Wi[(size_t)k * 100u + c] : 0.f);
    return;
  }
  i -= 57344u;
  if (i < 32768u) {                 // dtT[t][b] = td[b][t]
    unsigned t = i / 64u, b = i % 64u;
    dtT[i] = td[(size_t)b * 512u + t];
    return;
  }
  i -= 32768u;
  if (i < 65536u) { flags[i] = 0; return; }
}

// ---------------- zx = gather(embedding) @ W_x + b, stored bf16 in frag-permuted layout ----
__global__ __launch_bounds__(256, 2)
void zx_kernel(const int* __restrict__ evt, const unsigned short* __restrict__ embB,
               const unsigned short* __restrict__ WbT, const float* __restrict__ bias,
               unsigned short* __restrict__ zxp) {
  const int t = blockIdx.y;
  const int tid = threadIdx.x;
  const int v = tid >> 6, lane = tid & 63;
  const int m = lane & 15, quad = lane >> 4;
  const int cbase = blockIdx.x * 256 + v * 64;  // wave's 64 output cols (4 frags)

  // Preload B frags (W_x rows 0..255): Breg[ch][cf], k = ch*32 + quad*8 + j
  s16x8 Breg[8][4];
#pragma unroll
  for (int cf = 0; cf < 4; ++cf) {
    const unsigned short* bp = WbT + (size_t)(cbase + cf * 16 + m) * 768 + quad * 8;
#pragma unroll
    for (int ch = 0; ch < 8; ++ch) Breg[ch][cf] = *(const s16x8*)(bp + ch * 32);
  }
  int ev[4];
#pragma unroll
  for (int rt = 0; rt < 4; ++rt) ev[rt] = evt[(size_t)(rt * 16 + m) * 512 + t];

  vf4 acc[4][4];
#pragma unroll
  for (int cf = 0; cf < 4; ++cf) {
    float bbv = bias[cbase + cf * 16 + m];
#pragma unroll
    for (int rt = 0; rt < 4; ++rt) acc[rt][cf] = (vf4){bbv, bbv, bbv, bbv};
  }
#pragma unroll
  for (int ch = 0; ch < 8; ++ch) {
#pragma unroll
    for (int rt = 0; rt < 4; ++rt) {
      s16x8 a = *(const s16x8*)(embB + (size_t)ev[rt] * 256 + ch * 32 + quad * 8);
#pragma unroll
      for (int cf = 0; cf < 4; ++cf)
        acc[rt][cf] = __builtin_amdgcn_mfma_f32_16x16x32_bf16(a, Breg[ch][cf], acc[rt][cf], 0, 0, 0);
    }
  }
#pragma unroll
  for (int cf = 0; cf < 4; ++cf) {
    int col0 = cbase + cf * 16;
    int g = col0 >> 9;              // gate index
    int w = (col0 & 511) >> 4;      // scan WG owning these cols
#pragma unroll
    for (int rt = 0; rt < 4; ++rt) {
      unsigned h0 = f2bf(acc[rt][cf][0]);
      unsigned h1 = f2bf(acc[rt][cf][1]);
      unsigned h2 = f2bf(acc[rt][cf][2]);
      unsigned h3 = f2bf(acc[rt][cf][3]);
      uint2 val;
      val.x = h0 | (h1 << 16);
      val.y = h2 | (h3 << 16);
      ((uint2*)zxp)[((((size_t)t * 32 + w) * 4 + rt) * 5 + g) * 64 + lane] = val;
    }
  }
}

// ---------------- persistent sequential scan: 32 WGs, wave-to-wave flag sync ----------------
// Wave v of WG w owns batch rows [16v,16v+16) x hidden cols [16w,16w+16).
// Consumer wave v needs rows [16v,16v+16) x all cols == outputs of wave v of every WG.
// So sync is wave-granular: no __syncthreads anywhere in the loop.
__global__ __launch_bounds__(256, 1)
void scan_kernel(const unsigned short* __restrict__ WbT,
                 const unsigned short* __restrict__ zxp,
                 const float* __restrict__ dtT,
                 unsigned short* __restrict__ hbuf,
                 int* __restrict__ flags,
                 float* __restrict__ out_h, float* __restrict__ out_d) {
  const int w = blockIdx.x;           // 0..31, owns hidden cols [w*16, w*16+16)
  const int tid = threadIdx.x;
  const int v = tid >> 6, lane = tid & 63;
  const int m = lane & 15, quad = lane >> 4;
  const int rowb = v * 16;
  const int bb0 = rowb + quad * 4;    // first batch row of this lane's C-frag elems
  const int col = w * 16 + m;         // hidden col of this lane's C-frag elems

  // W_h slice resident in registers: Breg[ch][g], k = 256 + ch*32 + quad*8 + j
  s16x8 Breg[16][5];
#pragma unroll
  for (int g = 0; g < 5; ++g) {
    const unsigned short* bp = WbT + (size_t)(g * 512 + w * 16 + m) * 768 + 256 + quad * 8;
#pragma unroll
    for (int ch = 0; ch < 16; ++ch) Breg[ch][g] = *(const s16x8*)(bp + ch * 32);
  }

  vf4 cst = (vf4){0.f, 0.f, 0.f, 0.f};   // cell state (4 rows x this lane's col)

  for (int t = 0; t < 512; ++t) {
    // acc init from zx (independent of recurrence -> issued before the poll)
    vf4 acc[5];
#pragma unroll
    for (int g = 0; g < 5; ++g) {
      uint2 zv = ((const uint2*)zxp)[((((size_t)t * 32 + w) * 4 + v) * 5 + g) * 64 + lane];
      acc[g][0] = bf2f((unsigned short)(zv.x & 0xffffu));
      acc[g][1] = bf2f((unsigned short)(zv.x >> 16));
      acc[g][2] = bf2f((unsigned short)(zv.y & 0xffffu));
      acc[g][3] = bf2f((unsigned short)(zv.y >> 16));
    }
    vf4 dt4 = *(const vf4*)(dtT + t * 64 + bb0);

    if (t > 0) {
      const int tp = t - 1;
      // lane L < 32 polls producer WG L, wave v. One flag line per (w,v): 32 pollers/line.
      if (lane < 32) {
        const int* fp = flags + fidx(tp, lane, v);
        while (__hip_atomic_load(fp, __ATOMIC_RELAXED, __HIP_MEMORY_SCOPE_AGENT) == 0) {
          __builtin_amdgcn_s_sleep(1);
        }
      }
      // No HW acquire fence needed: hbuf[t-1] lines are first-touch on this CU and the
      // producer's sc1 stores reached the coherence point before its flag store.
      __asm__ __volatile__("" ::: "memory");
      const unsigned short* hsrc =
          hbuf + (size_t)tp * (BB * HH) + (size_t)(rowb + m) * HH + quad * 8;
#pragma unroll
      for (int ch = 0; ch < 16; ++ch) {
        s16x8 a = *(const s16x8*)(hsrc + ch * 32);
#pragma unroll
        for (int g = 0; g < 5; ++g)
          acc[g] = __builtin_amdgcn_mfma_f32_16x16x32_bf16(a, Breg[ch][g], acc[g], 0, 0, 0);
      }
    }

    // gates + state update; publish h (sc1, coherence point) on the critical path,
    // fp32 outputs deferred until after the flag store.
    float hv[4], dv[4];
#pragma unroll
    for (int r = 0; r < 4; ++r) {
      float i_ = sigmoidf_(acc[0][r]);
      float f_ = sigmoidf_(acc[1][r]);
      float o_ = sigmoidf_(acc[2][r]);
      float g_ = tanhf_(acc[3][r]);
      float dec = softplusf_(acc[4][r]);
      float cn = f_ * cst[r] + i_ * g_;
      float ct = cn * __expf(-dec * dt4[r]);
      float h_ = o_ * tanhf_(ct);
      cst[r] = ct;
      hv[r] = h_; dv[r] = dec;
      __hip_atomic_store(hbuf + (size_t)t * (BB * HH) + (size_t)(bb0 + r) * HH + col,
                         f2bf(h_), __ATOMIC_RELAXED, __HIP_MEMORY_SCOPE_AGENT);
    }
    // Drain this wave's sc1 h-stores, then publish. (Manual waitcnt instead of a
    // RELEASE store to avoid a possible buffer_wbl2 in the atomic-release lowering.)
    __asm__ __volatile__("" ::: "memory");
    __builtin_amdgcn_s_waitcnt(0);
    __asm__ __volatile__("" ::: "memory");
    if (lane == 0) {
      __hip_atomic_store(flags + fidx(t, w, v), 1, __ATOMIC_RELAXED,
                         __HIP_MEMORY_SCOPE_AGENT);
    }
    // Off-critical-path fp32 outputs (drained by next step's waitcnt, overlapped).
#pragma unroll
    for (int r = 0; r < 4; ++r) {
      size_t oo = ((size_t)(bb0 + r) * SS + t) * HH + col;
      out_h[oo] = hv[r];
      out_d[oo] = dv[r];
    }
  }
}

// ---------------- base_intensities = softplus(h @ Wi + bi) ----------------
__global__ __launch_bounds__(256, 2)
void inten_kernel(const unsigned short* __restrict__ hbuf,
                  const unsigned short* __restrict__ WiT,
                  const float* __restrict__ bi,
                  float* __restrict__ out_i) {
  const int b = blockIdx.y;            // batch row
  const int t0 = blockIdx.x * 64;      // 64 timesteps per WG
  const int tid = threadIdx.x;
  const int v = tid >> 6, lane = tid & 63;
  const int m = lane & 15, quad = lane >> 4;
  const int trow = t0 + v * 16 + m;    // A row = timestep

  vf4 acc[7];
#pragma unroll
  for (int cf = 0; cf < 7; ++cf) {
    int c = cf * 16 + m;
    float bbv = (c < 100) ? bi[c] : 0.f;
    acc[cf] = (vf4){bbv, bbv, bbv, bbv};
  }
  const unsigned short* ha = hbuf + ((size_t)trow * 64 + b) * 512 + quad * 8;
#pragma unroll 4
  for (int ch = 0; ch < 16; ++ch) {
    s16x8 a = *(const s16x8*)(ha + ch * 32);
#pragma unroll
    for (int cf = 0; cf < 7; ++cf) {
      s16x8 bf = *(const s16x8*)(WiT + (size_t)(cf * 16 + m) * 512 + ch * 32 + quad * 8);
      acc[cf] = __builtin_amdgcn_mfma_f32_16x16x32_bf16(a, bf, acc[cf], 0, 0, 0);
    }
  }
#pragma unroll
  for (int cf = 0; cf < 7; ++cf) {
    int c = cf * 16 + m;
#pragma unroll
    for (int r = 0; r < 4; ++r) {
      int tt = t0 + v * 16 + quad * 4 + r;
      if (c < 100) out_i[((size_t)b * 512 + tt) * 100 + c] = softplusf_(acc[cf][r]);
    }
  }
}

extern "C" void kernel_launch(void* const* d_in, const int* in_sizes, int n_in,
                              void* d_out, int out_size, void* d_ws, size_t ws_size,
                              hipStream_t stream) {
  (void)in_sizes; (void)n_in; (void)out_size; (void)ws_size;
  const int*   evt  = (const int*)d_in[0];
  const float* td   = (const float*)d_in[1];
  const float* emb  = (const float*)d_in[2];
  const float* W    = (const float*)d_in[3];
  const float* bias = (const float*)d_in[4];
  const float* Wi   = (const float*)d_in[5];
  const float* bi   = (const float*)d_in[6];

  char* ws = (char*)d_ws;
  unsigned short* WbT  = (unsigned short*)(ws + OFF_WBT);
  unsigned short* embB = (unsigned short*)(ws + OFF_EMB);
  unsigned short* WiT  = (unsigned short*)(ws + OFF_WIT);
  float*          dtT  = (float*)(ws + OFF_DTT);
  int*            flags= (int*)(ws + OFF_FLAGS);
  unsigned short* hbuf = (unsigned short*)(ws + OFF_HBUF);
  unsigned short* zxp  = (unsigned short*)(ws + OFF_ZXP);

  float* out_h = (float*)d_out;
  float* out_d = out_h + (size_t)BB * SS * HH;
  float* out_i = out_d + (size_t)BB * SS * HH;

  init_kernel<<<8390, 256, 0, stream>>>(W, emb, Wi, td, WbT, embB, WiT, dtT, flags);
  zx_kernel<<<dim3(10, 512), 256, 0, stream>>>(evt, embB, WbT, bias, zxp);
  scan_kernel<<<NWG, 256, 0, stream>>>(WbT, zxp, dtT, hbuf, flags, out_h, out_d);
  inten_kernel<<<dim3(8, 64), 256, 0, stream>>>(hbuf, WiT, bi, out_i);
}